// Round 14
// baseline (185.325 us; speedup 1.0000x reference)
//
#include <hip/hip_runtime.h>
#include <hip/hip_bf16.h>

using u16 = unsigned short;
using u32 = unsigned int;
typedef __attribute__((ext_vector_type(8))) short short8;  // 8 bf16 (4 VGPRs)
typedef __attribute__((ext_vector_type(4))) float f32x4;   // MFMA 16x16 C/D

#define MFMA16(A, B, C) __builtin_amdgcn_mfma_f32_16x16x32_bf16((A), (B), (C), 0, 0, 0)

// ---------- bf16 helpers ----------
__device__ __forceinline__ u16 f2bf(float f) {
  union { float f; u32 i; } v; v.f = f;
  u32 x = v.i;
  return (u16)((x + 0x7fffu + ((x >> 16) & 1u)) >> 16);  // RNE
}
__device__ __forceinline__ u32 pkbf(float a, float b) {
  union { __hip_bfloat162 h; u32 u; } v;
  v.h = __float22bfloat162_rn(make_float2(a, b));
  return v.u;
}
// HW packed f32->bf16 (RNE), 1 instr; no builtin on gfx950 (T12/m240)
__device__ __forceinline__ u32 cvtpk(float a, float b) {
  u32 r;
  asm("v_cvt_pk_bf16_f32 %0, %1, %2" : "=v"(r) : "v"(a), "v"(b));
  return r;
}
// async global->LDS, 16B/lane; LDS dest = wave-uniform base + lane*16
__device__ __forceinline__ void gl16(const u16* g, u16* l) {
  __builtin_amdgcn_global_load_lds(
      (const __attribute__((address_space(1))) u32*)g,
      (__attribute__((address_space(3))) u32*)l, 16, 0, 0);
}

// ============================================================
// Prep A: ft fp32 -> Xbf bf16 (16384x512)
// ============================================================
__global__ __launch_bounds__(256) void conv_x(const float* __restrict__ X,
                                              u16* __restrict__ Xbf) {
  const int i = (blockIdx.x * 256 + threadIdx.x) * 8;
  float4 a = *(const float4*)(X + i);
  float4 b = *(const float4*)(X + i + 4);
  uint4 o;
  o.x = pkbf(a.x, a.y); o.y = pkbf(a.z, a.w);
  o.z = pkbf(b.x, b.y); o.w = pkbf(b.z, b.w);
  *(uint4*)(Xbf + i) = o;
}

// ============================================================
// Prep B: transpose+convert W[512][N] fp32 -> Wt[N][512] bf16
// ============================================================
__global__ __launch_bounds__(256) void transpose_w(
    const float* __restrict__ Wq, const float* __restrict__ Wo,
    u16* __restrict__ Wqt, u16* __restrict__ Wot) {
  const int z = blockIdx.z;
  if (z == 1 && blockIdx.x >= 16) return;
  const float* src = z ? Wo : Wq;
  u16* dst = z ? Wot : Wqt;
  const int ncols = z ? 512 : 1536;
  __shared__ float tile[32][33];
  const int t = threadIdx.x;
  const int kt = blockIdx.y * 32, nt = blockIdx.x * 32;
  const int r = t >> 3, c4 = (t & 7) * 4;
  float4 v = *(const float4*)(src + (size_t)(kt + r) * ncols + nt + c4);
  tile[r][c4 + 0] = v.x; tile[r][c4 + 1] = v.y;
  tile[r][c4 + 2] = v.z; tile[r][c4 + 3] = v.w;
  __syncthreads();
  uint2 p = make_uint2(pkbf(tile[c4 + 0][r], tile[c4 + 1][r]),
                       pkbf(tile[c4 + 2][r], tile[c4 + 3][r]));
  *(uint2*)(dst + (size_t)(nt + r) * 512 + kt + c4) = p;
}

// ============================================================
// Kernel 1 v5: QKV GEMM, 512 thr / 128M x 256N, depth-2 counted-
// vmcnt pipeline (unchanged K-loop), NEW epilogue: Q/K accs bounce
// through the now-dead 72 KB staging LDS ([128][264] bf16, padded)
// and store as COALESCED uint4 (round-13 counters: WRITE 69 MB for
// 48 MB output = 1.44x amp from 2-byte scalar Q/K stores). V keeps
// its direct uint2 path (transposed layout; 32B segments combine).
// Staging arrays re-declared as one SM[] with explicit offsets so
// the bounce tile can legally alias them after the final barrier.
// ============================================================
__global__ __launch_bounds__(512) void qkv_gemm(
    const u16* __restrict__ Xbf, const u16* __restrict__ Wt,
    const float* __restrict__ Bias,
    u16* __restrict__ Qp, u16* __restrict__ Kp, u16* __restrict__ Vt) {
  __shared__ u16 SM[36864];  // 72 KB: X 3x[128][32] | W 3x[256][32]
  #define XS(b, r) (&SM[(b) * 4096 + (r) * 32])
  #define WS(b, r) (&SM[12288 + (b) * 8192 + (r) * 32])
  #define ES(r, c) SM[(r) * 264 + (c)]
  const int t = threadIdx.x;
  const int lid = blockIdx.y * 6 + blockIdx.x;        // 0..767
  const int sid = (lid & 7) * 96 + (lid >> 3);        // bijective XCD swizzle
  const int bm = (sid / 6) * 128, bn = (sid % 6) * 256;
  const int w = t >> 6, lane = t & 63, quad = lane >> 4, l16 = lane & 15;
  const int mtb = (w >> 2) * 64, ntb = (w & 3) * 64;  // wave tile 64x64
  const int rr = lane >> 2;
  const int gch = ((lane & 3) ^ ((lane >> 3) & 3)) * 8;
  const int sw = (quad ^ ((l16 >> 1) & 3)) * 8;

  const u16* xg0 = Xbf + (size_t)(bm + w * 16 + rr) * 512 + gch;
  const u16* wg0 = Wt + (size_t)(bn + w * 16 + rr) * 512 + gch;
  const u16* wg1 = wg0 + (size_t)128 * 512;

  f32x4 acc[4][4];
  const f32x4 z4 = {0.f, 0.f, 0.f, 0.f};
  #pragma unroll
  for (int mi = 0; mi < 4; mi++)
    #pragma unroll
    for (int ni = 0; ni < 4; ni++) acc[mi][ni] = z4;

  // ---- prologue: issue steps 0 and 1; wait only for step 0 ----
  gl16(xg0, XS(0, w * 16));
  gl16(wg0, WS(0, w * 16)); gl16(wg1, WS(0, w * 16 + 128));
  gl16(xg0 + 32, XS(1, w * 16));
  gl16(wg0 + 32, WS(1, w * 16)); gl16(wg1 + 32, WS(1, w * 16 + 128));
  asm volatile("s_waitcnt vmcnt(3)" ::: "memory");
  __builtin_amdgcn_s_barrier();

  for (int k = 0; k < 16; ++k) {
    const int cur = k % 3;
    if (k < 14) {                  // issue step k+2 (stays in flight)
      const int nx2 = (k + 2) % 3;
      const int kn = (k + 2) * 32;
      gl16(xg0 + kn, XS(nx2, w * 16));
      gl16(wg0 + kn, WS(nx2, w * 16));
      gl16(wg1 + kn, WS(nx2, w * 16 + 128));
    }
    short8 af[4], bf4[4];
    #pragma unroll
    for (int mi = 0; mi < 4; mi++)
      af[mi] = *(const short8*)(XS(cur, mtb + mi * 16 + l16) + sw);
    #pragma unroll
    for (int ni = 0; ni < 4; ni++)
      bf4[ni] = *(const short8*)(WS(cur, ntb + ni * 16 + l16) + sw);
    #pragma unroll
    for (int mi = 0; mi < 4; mi++)
      #pragma unroll
      for (int ni = 0; ni < 4; ni++)
        acc[mi][ni] = MFMA16(af[mi], bf4[ni], acc[mi][ni]);
    if (k < 15) {
      if (k < 14) asm volatile("s_waitcnt vmcnt(3) lgkmcnt(0)" ::: "memory");
      else        asm volatile("s_waitcnt vmcnt(0) lgkmcnt(0)" ::: "memory");
      __builtin_amdgcn_s_barrier();
    }
  }

  // ---- epilogue pass 0: V direct (uint2, as before); Q/K -> LDS
  //      bounce tile as bf16 with bias+qsc applied ----
  __syncthreads();   // all waves done reading staging LDS
  #pragma unroll
  for (int ni = 0; ni < 4; ni++) {
    const int g = bn + ntb + ni * 16;
    const int h = g / 192, rm = g % 192;
    const int type = rm >> 6, dbase = rm & 63;
    const float bias = Bias[g + l16];
    const float qsc = (type == 0) ? 0.125f * 1.44269504088896340736f : 1.0f;
    #pragma unroll
    for (int mi = 0; mi < 4; mi++) {
      if (type == 2) {  // V -> Vt[b][h][d][n] (direct, unchanged)
        const int row0 = bm + mtb + mi * 16 + quad * 4;
        const int b = row0 >> 10, n0 = row0 & 1023;
        const size_t bh = (size_t)(b * 8 + h) * 65536;
        uint2 p = make_uint2(pkbf(acc[mi][ni][0] + bias, acc[mi][ni][1] + bias),
                             pkbf(acc[mi][ni][2] + bias, acc[mi][ni][3] + bias));
        *(uint2*)(Vt + bh + (size_t)(dbase + l16) * 1024 + n0) = p;
      } else {          // Q/K -> bounce tile
        const int lrow = mtb + mi * 16 + quad * 4;
        const int lcol = ntb + ni * 16 + l16;
        #pragma unroll
        for (int r = 0; r < 4; r++)
          ES(lrow + r, lcol) = f2bf((acc[mi][ni][r] + bias) * qsc);
      }
    }
  }
  __syncthreads();
  // ---- epilogue pass 1: coalesced uint4 Q/K stores ----
  #pragma unroll
  for (int rep = 0; rep < 8; rep++) {
    const int row = rep * 16 + (t >> 5);   // 0..127
    const int ch = t & 31;                 // 8-col chunk
    const int g = bn + ch * 8;
    const int rm = g % 192;
    const int type = rm >> 6;
    if (type < 2) {
      const int h = g / 192;
      const int row0 = bm + row;
      const int b = row0 >> 10, n0 = row0 & 1023;
      uint4 v = *(const uint4*)&ES(row, ch * 8);
      u16* dst = (type ? Kp : Qp) + (size_t)(b * 8 + h) * 65536 +
                 (size_t)n0 * 64 + (rm & 63);
      *(uint4*)dst = v;
    }
  }
  #undef XS
  #undef WS
  #undef ES
}

// ============================================================
// Kernel 2 v13: flash attention, TWO query-tiles per wave (32 q).
// K/V-frag register loads feed MFMAs for BOTH q-tiles; LDS reads,
// DMA staging, K/V HBM traffic per query all halved. Grid 512 =
// 2 blocks/CU (8 waves, 32 KB). KVBLK=64, 2-phase dbuf, one
// __syncthreads/kt, S^T formulation, no P LDS, no online-max,
// pre-swizzled DMA source, cvt_pk pack, l = P*ones on MFMA pipe.
// (unchanged from round 13 -- left the top-5)
// ============================================================
__global__ __launch_bounds__(512, 4) void attn_mfma(
    const u16* __restrict__ Qp, const u16* __restrict__ Kp,
    const u16* __restrict__ Vt, u16* __restrict__ ATT) {
  __shared__ u16 Ks[2][64][64];   // [buf][key][d]   linear, swizzled content
  __shared__ u16 Vs[2][64][64];   // [buf][d][key]   linear, swizzled content
  const int t = threadIdx.x, w = t >> 6, lane = t & 63;
  const int quad = lane >> 4, l16 = lane & 15;
  const int bx = blockIdx.x;
  const int c = bx & 7, g = bx >> 3;     // c = XCD affinity
  const int qt = g & 3, u = g >> 2;      // qt 0..3, u 0..15
  const int bh_id = u * 8 + c;           // 0..127
  const int b = bh_id >> 3, h = bh_id & 7;
  const size_t bh = (size_t)bh_id * 65536;
  const u16* Qb = Qp + bh;
  const u16* Kb = Kp + bh;
  const u16* Vb = Vt + bh;
  const int q0 = qt * 256 + w * 32;      // wave owns queries q0..q0+31

  // ---- DMA source addresses (inverse-swizzled global chunks) ----
  const u16* kg = Kb + (size_t)(t >> 3) * 64 + ((t & 7) ^ ((t >> 3) & 7)) * 8;
  const u16* vg = Vb + (size_t)(t >> 3) * 1024 + ((t & 7) ^ ((t >> 3) & 7)) * 8;
  // wave-uniform LDS dests (1 KiB per wave), per buffer
  u16* ks0 = &Ks[0][0][0] + w * 512;
  u16* ks1 = &Ks[1][0][0] + w * 512;
  u16* vs0 = &Vs[0][0][0] + w * 512;
  u16* vs1 = &Vs[1][0][0] + w * 512;

  // ---- read-side swizzled base offsets (bytes), hoisted ----
  const int m7 = l16 & 7;
  const char* ksb = (const char*)&Ks[0][0][0];
  const char* vsb = (const char*)&Vs[0][0][0];
  const int kb0 = l16 * 128 + (quad ^ m7) * 16;   // d-chunk quad
  const int kb1 = kb0 ^ 64;                       // d-chunk quad+4
  int vo[2];
  #pragma unroll
  for (int ks = 0; ks < 2; ks++)                  // key-chunk 4ks+quad
    vo[ks] = l16 * 128 + ((4 * ks + quad) ^ m7) * 16;

  // Q frags for BOTH q-tiles (B-operand for S^T): 16 regs
  short8 qfA[2], qfB[2];
  #pragma unroll
  for (int ks = 0; ks < 2; ks++) {
    qfA[ks] = *(const short8*)(Qb + (size_t)(q0 + l16) * 64 + ks * 32 + quad * 8);
    qfB[ks] = *(const short8*)(Qb + (size_t)(q0 + 16 + l16) * 64 + ks * 32 + quad * 8);
  }

  // all-ones bf16 B-fragment (1.0 = 0x3F80) for the l = P*ones tiles
  const short8 vone = {(short)0x3F80, (short)0x3F80, (short)0x3F80,
                       (short)0x3F80, (short)0x3F80, (short)0x3F80,
                       (short)0x3F80, (short)0x3F80};

  f32x4 OfA[4], OfB[4], OlA, OlB;
  const f32x4 z4 = {0.f, 0.f, 0.f, 0.f};
  #pragma unroll
  for (int ni = 0; ni < 4; ni++) { OfA[ni] = z4; OfB[ni] = z4; }
  OlA = z4; OlB = z4;

  // ---- prologue: stage tile 0 into buffer 0 ----
  gl16(kg, ks0);
  gl16(vg, vs0);
  __syncthreads();   // drain prologue DMA

  for (int kt = 0; kt < 16; ++kt) {   // runtime loop (v8 spill lesson)
    const int cur = kt & 1;
    if (kt < 15) {
      gl16(kg + (kt + 1) * 4096, cur ? ks0 : ks1);
      gl16(vg + (kt + 1) * 64,   cur ? vs0 : vs1);
    }
    const int co = cur << 13;  // byte offset of current buffer (8192)

    // ---- S^T tiles + fused softmax/pack for BOTH q-tiles.
    //      K-frags read ONCE, used twice. ----
    u32 eA[4], oA[4], eB[4], oB[4];
    #pragma unroll
    for (int nt = 0; nt < 4; nt++) {
      short8 k0f = *(const short8*)(ksb + co + kb0 + nt * 2048);
      short8 k1f = *(const short8*)(ksb + co + kb1 + nt * 2048);
      f32x4 sA = z4, sB = z4;
      sA = MFMA16(k0f, qfA[0], sA);
      sB = MFMA16(k0f, qfB[0], sB);
      sA = MFMA16(k1f, qfA[1], sA);
      sB = MFMA16(k1f, qfB[1], sB);
      float a0 = __builtin_amdgcn_exp2f(sA[0]);
      float a1 = __builtin_amdgcn_exp2f(sA[1]);
      float a2 = __builtin_amdgcn_exp2f(sA[2]);
      float a3 = __builtin_amdgcn_exp2f(sA[3]);
      float b0 = __builtin_amdgcn_exp2f(sB[0]);
      float b1 = __builtin_amdgcn_exp2f(sB[1]);
      float b2 = __builtin_amdgcn_exp2f(sB[2]);
      float b3 = __builtin_amdgcn_exp2f(sB[3]);
      const u32 loA = cvtpk(a0, a1), hiA = cvtpk(a2, a3);
      const u32 loB = cvtpk(b0, b1), hiB = cvtpk(b2, b3);
      if (nt & 1) {
        oA[(nt >> 1) * 2] = loA; oA[(nt >> 1) * 2 + 1] = hiA;
        oB[(nt >> 1) * 2] = loB; oB[(nt >> 1) * 2 + 1] = hiB;
      } else {
        eA[(nt >> 1) * 2] = loA; eA[(nt >> 1) * 2 + 1] = hiA;
        eB[(nt >> 1) * 2] = loB; eB[(nt >> 1) * 2 + 1] = hiB;
      }
    }
    // ---- cross-quad P redistribution, in-register, IN PLACE ----
    #pragma unroll
    for (int i = 0; i < 4; i++) {
      auto tA = __builtin_amdgcn_permlane32_swap(eA[i], oA[i], false, false);
      auto xA = __builtin_amdgcn_permlane16_swap(tA[0], tA[1], false, false);
      eA[i] = xA[0]; oA[i] = xA[1];
      auto tB = __builtin_amdgcn_permlane32_swap(eB[i], oB[i], false, false);
      auto xB = __builtin_amdgcn_permlane16_swap(tB[0], tB[1], false, false);
      eB[i] = xB[0]; oB[i] = xB[1];
    }
    // ---- O += P V (16 MFMA) and l += P*1 (4 MFMA);
    //      V-frags read ONCE, used twice ----
    #pragma unroll
    for (int ks = 0; ks < 2; ks++) {
      union { short8 v; u32 u[4]; } paA, paB;
      paA.u[0] = eA[2 * ks]; paA.u[1] = eA[2 * ks + 1];
      paA.u[2] = oA[2 * ks]; paA.u[3] = oA[2 * ks + 1];
      paB.u[0] = eB[2 * ks]; paB.u[1] = eB[2 * ks + 1];
      paB.u[2] = oB[2 * ks]; paB.u[3] = oB[2 * ks + 1];
      #pragma unroll
      for (int ni = 0; ni < 4; ni++) {
        short8 vf = *(const short8*)(vsb + co + vo[ks] + ni * 2048);
        OfA[ni] = MFMA16(paA.v, vf, OfA[ni]);
        OfB[ni] = MFMA16(paB.v, vf, OfB[ni]);
      }
      OlA = MFMA16(paA.v, vone, OlA);
      OlB = MFMA16(paB.v, vone, OlB);
    }
    // ONE barrier per kt: implicit vmcnt(0) drains next-tile DMA;
    // also fences this buffer's reads before kt+1 overwrites it.
    __syncthreads();
  }
  // ---- epilogue: Ol[r] = l(query quad*4+r) in-lane, no shuffles ----
  #pragma unroll
  for (int r = 0; r < 4; r++) {
    const float invA = 1.0f / OlA[r];
    const float invB = 1.0f / OlB[r];
    const int rowA = b * 1024 + q0 + quad * 4 + r;
    const int rowB = rowA + 16;
    #pragma unroll
    for (int ni = 0; ni < 4; ni++) {
      ATT[(size_t)rowA * 512 + h * 64 + ni * 16 + l16] = f2bf(OfA[ni][r] * invA);
      ATT[(size_t)rowB * 512 + h * 64 + ni * 16 + l16] = f2bf(OfB[ni][r] * invB);
    }
  }
}

// ============================================================
// Kernel 3 v4: OUT = ATT(bf16) @ Wout^T + bias + ft(f32) -> f32
// 512 threads / 8 waves, 128x128 tile, wave-tile 32x64.
// Depth-2 counted-vmcnt pipeline (unchanged from round 12).
// ============================================================
__global__ __launch_bounds__(512) void out_proj(
    const u16* __restrict__ A, const u16* __restrict__ Wt,
    const float* __restrict__ Bias, const float* __restrict__ FT,
    float* __restrict__ OUT) {
  __shared__ u16 As[3][128][32];  // 8 KB/buf
  __shared__ u16 Ws[3][128][32];  // 8 KB/buf -> 48 KB total
  const int t = threadIdx.x;
  const int lid = blockIdx.y * 4 + blockIdx.x;        // 0..511
  const int sid = (lid & 7) * 64 + (lid >> 3);        // bijective
  const int bm = (sid / 4) * 128, bn = (sid % 4) * 128;
  const int w = t >> 6, lane = t & 63, quad = lane >> 4, l16 = lane & 15;
  const int mtb = (w >> 1) * 32, ntb = (w & 1) * 64;  // wave tile 32x64
  const int rr = lane >> 2;
  const int gch = ((lane & 3) ^ ((lane >> 3) & 3)) * 8;
  const int sw = (quad ^ ((l16 >> 1) & 3)) * 8;

  const u16* ag = A + (size_t)(bm + w * 16 + rr) * 512 + gch;
  const u16* wg = Wt + (size_t)(bn + w * 16 + rr) * 512 + gch;

  f32x4 acc[2][4];
  const f32x4 z4 = {0.f, 0.f, 0.f, 0.f};
  #pragma unroll
  for (int mi = 0; mi < 2; mi++)
    #pragma unroll
    for (int ni = 0; ni < 4; ni++) acc[mi][ni] = z4;

  // ---- prologue: issue steps 0 and 1; wait only for step 0 ----
  gl16(ag, &As[0][w * 16][0]);      gl16(wg, &Ws[0][w * 16][0]);
  gl16(ag + 32, &As[1][w * 16][0]); gl16(wg + 32, &Ws[1][w * 16][0]);
  asm volatile("s_waitcnt vmcnt(2)" ::: "memory");
  __builtin_amdgcn_s_barrier();

  for (int k = 0; k < 16; ++k) {
    const int cur = k % 3;
    if (k < 14) {                  // issue step k+2 (stays in flight)
      const int nx2 = (k + 2) % 3;
      const int kn = (k + 2) * 32;
      gl16(ag + kn, &As[nx2][w * 16][0]);
      gl16(wg + kn, &Ws[nx2][w * 16][0]);
    }
    short8 af[2], bf4[4];
    #pragma unroll
    for (int mi = 0; mi < 2; mi++)
      af[mi] = *(const short8*)&As[cur][mtb + mi * 16 + l16][sw];
    #pragma unroll
    for (int ni = 0; ni < 4; ni++)
      bf4[ni] = *(const short8*)&Ws[cur][ntb + ni * 16 + l16][sw];
    #pragma unroll
    for (int mi = 0; mi < 2; mi++)
      #pragma unroll
      for (int ni = 0; ni < 4; ni++)
        acc[mi][ni] = MFMA16(af[mi], bf4[ni], acc[mi][ni]);
    if (k < 15) {
      if (k < 14) asm volatile("s_waitcnt vmcnt(2) lgkmcnt(0)" ::: "memory");
      else        asm volatile("s_waitcnt vmcnt(0) lgkmcnt(0)" ::: "memory");
      __builtin_amdgcn_s_barrier();
    }
  }

  #pragma unroll
  for (int ni = 0; ni < 4; ni++) {
    const int g = bn + ntb + ni * 16;
    const float bias = Bias[g + l16];
    #pragma unroll
    for (int mi = 0; mi < 2; mi++) {
      const int row0 = bm + mtb + mi * 16 + quad * 4;
      #pragma unroll
      for (int r = 0; r < 4; r++) {
        const size_t idx = (size_t)(row0 + r) * 512 + g + l16;
        OUT[idx] = acc[mi][ni][r] + bias + FT[idx];
      }
    }
  }
}

// ============================================================
extern "C" void kernel_launch(void* const* d_in, const int* in_sizes, int n_in,
                              void* d_out, int out_size, void* d_ws, size_t ws_size,
                              hipStream_t stream) {
  const float* ft    = (const float*)d_in[0];  // [16][1024][512] f32
  const float* w_qkv = (const float*)d_in[1];  // [512][1536]   f32
  const float* b_qkv = (const float*)d_in[2];  // [1536]        f32
  const float* w_out = (const float*)d_in[3];  // [512][512]    f32
  const float* b_out = (const float*)d_in[4];  // [512]         f32
  float* out = (float*)d_out;                  // [16][1024][512] f32

  char* p = (char*)d_ws;
  u16* Xbf    = (u16*)(p);                              // 16,777,216
  u16* ATT    = Xbf;                                    // alias (Xbf dead)
  u16* Wqkv_t = (u16*)(p + 16777216);                   //  1,572,864
  u16* Wout_t = (u16*)(p + 18350080);                   //    524,288
  u16* Qp     = (u16*)(p + 18874368);                   // 16,777,216 (pre-scaled)
  u16* Kp     = (u16*)(p + 35651584);                   // 16,777,216
  u16* Vt     = (u16*)(p + 52428800);                   // 16,777,216 -> 69.2 MB

  conv_x     <<<4096, 256, 0, stream>>>(ft, Xbf);
  transpose_w<<<dim3(48, 16, 2), 256, 0, stream>>>(w_qkv, w_out, Wqkv_t, Wout_t);
  qkv_gemm   <<<dim3(6, 128), 512, 0, stream>>>(Xbf, Wqkv_t, b_qkv, Qp, Kp, Vt);
  attn_mfma  <<<dim3(512), 512, 0, stream>>>(Qp, Kp, Vt, ATT);
  out_proj   <<<dim3(4, 128), 512, 0, stream>>>(ATT, Wout_t, b_out, ft, out);
}

// Round 16
// 182.415 us; speedup vs baseline: 1.0159x; 1.0159x over previous
//
#include <hip/hip_runtime.h>
#include <hip/hip_bf16.h>

using u16 = unsigned short;
using u32 = unsigned int;
typedef __attribute__((ext_vector_type(8))) short short8;  // 8 bf16 (4 VGPRs)
typedef __attribute__((ext_vector_type(4))) float f32x4;   // MFMA 16x16 C/D

#define MFMA16(A, B, C) __builtin_amdgcn_mfma_f32_16x16x32_bf16((A), (B), (C), 0, 0, 0)

// ---------- bf16 helpers ----------
__device__ __forceinline__ u16 f2bf(float f) {
  union { float f; u32 i; } v; v.f = f;
  u32 x = v.i;
  return (u16)((x + 0x7fffu + ((x >> 16) & 1u)) >> 16);  // RNE
}
__device__ __forceinline__ u32 pkbf(float a, float b) {
  union { __hip_bfloat162 h; u32 u; } v;
  v.h = __float22bfloat162_rn(make_float2(a, b));
  return v.u;
}
// HW packed f32->bf16 (RNE), 1 instr; no builtin on gfx950 (T12/m240)
__device__ __forceinline__ u32 cvtpk(float a, float b) {
  u32 r;
  asm("v_cvt_pk_bf16_f32 %0, %1, %2" : "=v"(r) : "v"(a), "v"(b));
  return r;
}
// async global->LDS, 16B/lane; LDS dest = wave-uniform base + lane*16
__device__ __forceinline__ void gl16(const u16* g, u16* l) {
  __builtin_amdgcn_global_load_lds(
      (const __attribute__((address_space(1))) u32*)g,
      (__attribute__((address_space(3))) u32*)l, 16, 0, 0);
}

// ============================================================
// Prep A: ft fp32 -> Xbf bf16 (16384x512)
// ============================================================
__global__ __launch_bounds__(256) void conv_x(const float* __restrict__ X,
                                              u16* __restrict__ Xbf) {
  const int i = (blockIdx.x * 256 + threadIdx.x) * 8;
  float4 a = *(const float4*)(X + i);
  float4 b = *(const float4*)(X + i + 4);
  uint4 o;
  o.x = pkbf(a.x, a.y); o.y = pkbf(a.z, a.w);
  o.z = pkbf(b.x, b.y); o.w = pkbf(b.z, b.w);
  *(uint4*)(Xbf + i) = o;
}

// ============================================================
// Prep B: transpose+convert W[512][N] fp32 -> Wt[N][512] bf16
// ============================================================
__global__ __launch_bounds__(256) void transpose_w(
    const float* __restrict__ Wq, const float* __restrict__ Wo,
    u16* __restrict__ Wqt, u16* __restrict__ Wot) {
  const int z = blockIdx.z;
  if (z == 1 && blockIdx.x >= 16) return;
  const float* src = z ? Wo : Wq;
  u16* dst = z ? Wot : Wqt;
  const int ncols = z ? 512 : 1536;
  __shared__ float tile[32][33];
  const int t = threadIdx.x;
  const int kt = blockIdx.y * 32, nt = blockIdx.x * 32;
  const int r = t >> 3, c4 = (t & 7) * 4;
  float4 v = *(const float4*)(src + (size_t)(kt + r) * ncols + nt + c4);
  tile[r][c4 + 0] = v.x; tile[r][c4 + 1] = v.y;
  tile[r][c4 + 2] = v.z; tile[r][c4 + 3] = v.w;
  __syncthreads();
  uint2 p = make_uint2(pkbf(tile[c4 + 0][r], tile[c4 + 1][r]),
                       pkbf(tile[c4 + 2][r], tile[c4 + 3][r]));
  *(uint2*)(dst + (size_t)(nt + r) * 512 + kt + c4) = p;
}

// ============================================================
// Kernel 1 v5: QKV GEMM, 512 thr / 128M x 256N, depth-2 counted-
// vmcnt pipeline; coalesced-uint4 Q/K epilogue via LDS bounce.
// (unchanged from round 14)
// ============================================================
__global__ __launch_bounds__(512) void qkv_gemm(
    const u16* __restrict__ Xbf, const u16* __restrict__ Wt,
    const float* __restrict__ Bias,
    u16* __restrict__ Qp, u16* __restrict__ Kp, u16* __restrict__ Vt) {
  __shared__ u16 SM[36864];  // 72 KB: X 3x[128][32] | W 3x[256][32]
  #define XS(b, r) (&SM[(b) * 4096 + (r) * 32])
  #define WS(b, r) (&SM[12288 + (b) * 8192 + (r) * 32])
  #define ES(r, c) SM[(r) * 264 + (c)]
  const int t = threadIdx.x;
  const int lid = blockIdx.y * 6 + blockIdx.x;        // 0..767
  const int sid = (lid & 7) * 96 + (lid >> 3);        // bijective XCD swizzle
  const int bm = (sid / 6) * 128, bn = (sid % 6) * 256;
  const int w = t >> 6, lane = t & 63, quad = lane >> 4, l16 = lane & 15;
  const int mtb = (w >> 2) * 64, ntb = (w & 3) * 64;  // wave tile 64x64
  const int rr = lane >> 2;
  const int gch = ((lane & 3) ^ ((lane >> 3) & 3)) * 8;
  const int sw = (quad ^ ((l16 >> 1) & 3)) * 8;

  const u16* xg0 = Xbf + (size_t)(bm + w * 16 + rr) * 512 + gch;
  const u16* wg0 = Wt + (size_t)(bn + w * 16 + rr) * 512 + gch;
  const u16* wg1 = wg0 + (size_t)128 * 512;

  f32x4 acc[4][4];
  const f32x4 z4 = {0.f, 0.f, 0.f, 0.f};
  #pragma unroll
  for (int mi = 0; mi < 4; mi++)
    #pragma unroll
    for (int ni = 0; ni < 4; ni++) acc[mi][ni] = z4;

  // ---- prologue: issue steps 0 and 1; wait only for step 0 ----
  gl16(xg0, XS(0, w * 16));
  gl16(wg0, WS(0, w * 16)); gl16(wg1, WS(0, w * 16 + 128));
  gl16(xg0 + 32, XS(1, w * 16));
  gl16(wg0 + 32, WS(1, w * 16)); gl16(wg1 + 32, WS(1, w * 16 + 128));
  asm volatile("s_waitcnt vmcnt(3)" ::: "memory");
  __builtin_amdgcn_s_barrier();

  for (int k = 0; k < 16; ++k) {
    const int cur = k % 3;
    if (k < 14) {                  // issue step k+2 (stays in flight)
      const int nx2 = (k + 2) % 3;
      const int kn = (k + 2) * 32;
      gl16(xg0 + kn, XS(nx2, w * 16));
      gl16(wg0 + kn, WS(nx2, w * 16));
      gl16(wg1 + kn, WS(nx2, w * 16 + 128));
    }
    short8 af[4], bf4[4];
    #pragma unroll
    for (int mi = 0; mi < 4; mi++)
      af[mi] = *(const short8*)(XS(cur, mtb + mi * 16 + l16) + sw);
    #pragma unroll
    for (int ni = 0; ni < 4; ni++)
      bf4[ni] = *(const short8*)(WS(cur, ntb + ni * 16 + l16) + sw);
    #pragma unroll
    for (int mi = 0; mi < 4; mi++)
      #pragma unroll
      for (int ni = 0; ni < 4; ni++)
        acc[mi][ni] = MFMA16(af[mi], bf4[ni], acc[mi][ni]);
    if (k < 15) {
      if (k < 14) asm volatile("s_waitcnt vmcnt(3) lgkmcnt(0)" ::: "memory");
      else        asm volatile("s_waitcnt vmcnt(0) lgkmcnt(0)" ::: "memory");
      __builtin_amdgcn_s_barrier();
    }
  }

  // ---- epilogue pass 0: V direct (uint2); Q/K -> LDS bounce tile ----
  __syncthreads();   // all waves done reading staging LDS
  #pragma unroll
  for (int ni = 0; ni < 4; ni++) {
    const int g = bn + ntb + ni * 16;
    const int h = g / 192, rm = g % 192;
    const int type = rm >> 6, dbase = rm & 63;
    const float bias = Bias[g + l16];
    const float qsc = (type == 0) ? 0.125f * 1.44269504088896340736f : 1.0f;
    #pragma unroll
    for (int mi = 0; mi < 4; mi++) {
      if (type == 2) {  // V -> Vt[b][h][d][n] (direct, unchanged)
        const int row0 = bm + mtb + mi * 16 + quad * 4;
        const int b = row0 >> 10, n0 = row0 & 1023;
        const size_t bh = (size_t)(b * 8 + h) * 65536;
        uint2 p = make_uint2(pkbf(acc[mi][ni][0] + bias, acc[mi][ni][1] + bias),
                             pkbf(acc[mi][ni][2] + bias, acc[mi][ni][3] + bias));
        *(uint2*)(Vt + bh + (size_t)(dbase + l16) * 1024 + n0) = p;
      } else {          // Q/K -> bounce tile
        const int lrow = mtb + mi * 16 + quad * 4;
        const int lcol = ntb + ni * 16 + l16;
        #pragma unroll
        for (int r = 0; r < 4; r++)
          ES(lrow + r, lcol) = f2bf((acc[mi][ni][r] + bias) * qsc);
      }
    }
  }
  __syncthreads();
  // ---- epilogue pass 1: coalesced uint4 Q/K stores ----
  #pragma unroll
  for (int rep = 0; rep < 8; rep++) {
    const int row = rep * 16 + (t >> 5);   // 0..127
    const int ch = t & 31;                 // 8-col chunk
    const int g = bn + ch * 8;
    const int rm = g % 192;
    const int type = rm >> 6;
    if (type < 2) {
      const int h = g / 192;
      const int row0 = bm + row;
      const int b = row0 >> 10, n0 = row0 & 1023;
      uint4 v = *(const uint4*)&ES(row, ch * 8);
      u16* dst = (type ? Kp : Qp) + (size_t)(b * 8 + h) * 65536 +
                 (size_t)n0 * 64 + (rm & 63);
      *(uint4*)dst = v;
    }
  }
  #undef XS
  #undef WS
  #undef ES
}

// ============================================================
// Kernel 2 v14b: flash attention, TWO q-tiles/wave + SYMMETRIC
// depth-2 counted-vmcnt pipeline: 3 K-bufs AND 3 V-bufs (48 KB;
// free at 2 blocks/CU). Stall arithmetic (round 14): ~3100 cy/kt
// vs ~1000 cy compute => ~2000 cy exposed DMA latency; depth-1
// gives each tile only ONE compute phase (< 900 cy HBM latency).
// Protocol (vmcnt oldest-first): prologue pairs 0,1 -> vmcnt(2) ->
// bar. kt<=13: issue pair(kt+2) -> compute buf kt%3 -> vmcnt(2)
// [pair(kt+1) landed; pair(kt+2) IN FLIGHT across barrier] + bar;
// kt=14: vmcnt(0). WAR: pair(kt+2) writes buf (kt-1)%3, whose
// reads (all waves) are fenced by kt-1's lgkmcnt(0)+barrier.
// setprio only around the PV cluster (de-risk vs round 15).
// ============================================================
__global__ __launch_bounds__(512, 4) void attn_mfma(
    const u16* __restrict__ Qp, const u16* __restrict__ Kp,
    const u16* __restrict__ Vt, u16* __restrict__ ATT) {
  __shared__ u16 Ks[3][64][64];   // [buf][key][d]  24 KB, swizzled content
  __shared__ u16 Vs[3][64][64];   // [buf][d][key]  24 KB, swizzled content
  const int t = threadIdx.x, w = t >> 6, lane = t & 63;
  const int quad = lane >> 4, l16 = lane & 15;
  const int bx = blockIdx.x;
  const int c = bx & 7, g = bx >> 3;     // c = XCD affinity
  const int qt = g & 3, u = g >> 2;      // qt 0..3, u 0..15
  const int bh_id = u * 8 + c;           // 0..127
  const int b = bh_id >> 3, h = bh_id & 7;
  const size_t bh = (size_t)bh_id * 65536;
  const u16* Qb = Qp + bh;
  const u16* Kb = Kp + bh;
  const u16* Vb = Vt + bh;
  const int q0 = qt * 256 + w * 32;      // wave owns queries q0..q0+31

  // ---- DMA source addresses (inverse-swizzled global chunks) ----
  const u16* kg = Kb + (size_t)(t >> 3) * 64 + ((t & 7) ^ ((t >> 3) & 7)) * 8;
  const u16* vg = Vb + (size_t)(t >> 3) * 1024 + ((t & 7) ^ ((t >> 3) & 7)) * 8;
  // wave-uniform LDS dest bases (u16 units; buffer stride 4096 u16 = 8 KB)
  u16* ksW = &Ks[0][0][0] + w * 512;
  u16* vsW = &Vs[0][0][0] + w * 512;

  // ---- read-side swizzled base offsets (bytes), hoisted ----
  const int m7 = l16 & 7;
  const char* ksb = (const char*)&Ks[0][0][0];
  const char* vsb = (const char*)&Vs[0][0][0];
  const int kb0 = l16 * 128 + (quad ^ m7) * 16;   // d-chunk quad
  const int kb1 = kb0 ^ 64;                       // d-chunk quad+4
  int vo[2];
  #pragma unroll
  for (int ks = 0; ks < 2; ks++)                  // key-chunk 4ks+quad
    vo[ks] = l16 * 128 + ((4 * ks + quad) ^ m7) * 16;

  // Q frags for BOTH q-tiles (B-operand for S^T): 16 regs
  short8 qfA[2], qfB[2];
  #pragma unroll
  for (int ks = 0; ks < 2; ks++) {
    qfA[ks] = *(const short8*)(Qb + (size_t)(q0 + l16) * 64 + ks * 32 + quad * 8);
    qfB[ks] = *(const short8*)(Qb + (size_t)(q0 + 16 + l16) * 64 + ks * 32 + quad * 8);
  }

  // all-ones bf16 B-fragment (1.0 = 0x3F80) for the l = P*ones tiles
  const short8 vone = {(short)0x3F80, (short)0x3F80, (short)0x3F80,
                       (short)0x3F80, (short)0x3F80, (short)0x3F80,
                       (short)0x3F80, (short)0x3F80};

  f32x4 OfA[4], OfB[4], OlA, OlB;
  const f32x4 z4 = {0.f, 0.f, 0.f, 0.f};
  #pragma unroll
  for (int ni = 0; ni < 4; ni++) { OfA[ni] = z4; OfB[ni] = z4; }
  OlA = z4; OlB = z4;

  // ---- prologue: pairs 0 and 1; wait only for pair 0 ----
  gl16(kg, ksW);               gl16(vg, vsW);
  gl16(kg + 4096, ksW + 4096); gl16(vg + 64, vsW + 4096);
  asm volatile("s_waitcnt vmcnt(2)" ::: "memory");
  __builtin_amdgcn_s_barrier();

  int c3 = 0, n3 = 2;   // kt%3 and (kt+2)%3 as mod-counters
  for (int kt = 0; kt < 16; ++kt) {   // runtime loop (v8 spill lesson)
    if (kt < 14) {   // issue pair(kt+2); stays in flight across barrier
      gl16(kg + (kt + 2) * 4096, ksW + n3 * 4096);
      gl16(vg + (kt + 2) * 64,   vsW + n3 * 4096);
    }
    const int co = c3 * 8192;  // current buffer byte offset

    // ---- S^T tiles + fused softmax/pack for BOTH q-tiles.
    //      K-frags read ONCE, used twice. ----
    u32 eA[4], oA[4], eB[4], oB[4];
    #pragma unroll
    for (int nt = 0; nt < 4; nt++) {
      short8 k0f = *(const short8*)(ksb + co + kb0 + nt * 2048);
      short8 k1f = *(const short8*)(ksb + co + kb1 + nt * 2048);
      f32x4 sA = z4, sB = z4;
      sA = MFMA16(k0f, qfA[0], sA);
      sB = MFMA16(k0f, qfB[0], sB);
      sA = MFMA16(k1f, qfA[1], sA);
      sB = MFMA16(k1f, qfB[1], sB);
      float a0 = __builtin_amdgcn_exp2f(sA[0]);
      float a1 = __builtin_amdgcn_exp2f(sA[1]);
      float a2 = __builtin_amdgcn_exp2f(sA[2]);
      float a3 = __builtin_amdgcn_exp2f(sA[3]);
      float b0 = __builtin_amdgcn_exp2f(sB[0]);
      float b1 = __builtin_amdgcn_exp2f(sB[1]);
      float b2 = __builtin_amdgcn_exp2f(sB[2]);
      float b3 = __builtin_amdgcn_exp2f(sB[3]);
      const u32 loA = cvtpk(a0, a1), hiA = cvtpk(a2, a3);
      const u32 loB = cvtpk(b0, b1), hiB = cvtpk(b2, b3);
      if (nt & 1) {
        oA[(nt >> 1) * 2] = loA; oA[(nt >> 1) * 2 + 1] = hiA;
        oB[(nt >> 1) * 2] = loB; oB[(nt >> 1) * 2 + 1] = hiB;
      } else {
        eA[(nt >> 1) * 2] = loA; eA[(nt >> 1) * 2 + 1] = hiA;
        eB[(nt >> 1) * 2] = loB; eB[(nt >> 1) * 2 + 1] = hiB;
      }
    }
    // ---- cross-quad P redistribution, in-register, IN PLACE ----
    #pragma unroll
    for (int i = 0; i < 4; i++) {
      auto tA = __builtin_amdgcn_permlane32_swap(eA[i], oA[i], false, false);
      auto xA = __builtin_amdgcn_permlane16_swap(tA[0], tA[1], false, false);
      eA[i] = xA[0]; oA[i] = xA[1];
      auto tB = __builtin_amdgcn_permlane32_swap(eB[i], oB[i], false, false);
      auto xB = __builtin_amdgcn_permlane16_swap(tB[0], tB[1], false, false);
      eB[i] = xB[0]; oB[i] = xB[1];
    }
    // ---- O += P V (16 MFMA) and l += P*1 (4 MFMA);
    //      V-frags read ONCE, used twice ----
    __builtin_amdgcn_s_setprio(1);
    #pragma unroll
    for (int ks = 0; ks < 2; ks++) {
      union { short8 v; u32 u[4]; } paA, paB;
      paA.u[0] = eA[2 * ks]; paA.u[1] = eA[2 * ks + 1];
      paA.u[2] = oA[2 * ks]; paA.u[3] = oA[2 * ks + 1];
      paB.u[0] = eB[2 * ks]; paB.u[1] = eB[2 * ks + 1];
      paB.u[2] = oB[2 * ks]; paB.u[3] = oB[2 * ks + 1];
      #pragma unroll
      for (int ni = 0; ni < 4; ni++) {
        short8 vf = *(const short8*)(vsb + co + vo[ks] + ni * 2048);
        OfA[ni] = MFMA16(paA.v, vf, OfA[ni]);
        OfB[ni] = MFMA16(paB.v, vf, OfB[ni]);
      }
      OlA = MFMA16(paA.v, vone, OlA);
      OlB = MFMA16(paB.v, vone, OlB);
    }
    __builtin_amdgcn_s_setprio(0);
    // counted wait: pair(kt+1) landed; pair(kt+2) stays in flight.
    // lgkmcnt(0): this buffer's ds_reads done before kt+1's DMA
    // overwrites buf (kt+3)%3 = kt%3.
    if (kt < 15) {
      if (kt < 14) asm volatile("s_waitcnt vmcnt(2) lgkmcnt(0)" ::: "memory");
      else         asm volatile("s_waitcnt vmcnt(0) lgkmcnt(0)" ::: "memory");
      __builtin_amdgcn_s_barrier();
    }
    c3 = (c3 == 2) ? 0 : c3 + 1;
    n3 = (n3 == 2) ? 0 : n3 + 1;
  }
  // ---- epilogue: Ol[r] = l(query quad*4+r) in-lane, no shuffles ----
  #pragma unroll
  for (int r = 0; r < 4; r++) {
    const float invA = 1.0f / OlA[r];
    const float invB = 1.0f / OlB[r];
    const int rowA = b * 1024 + q0 + quad * 4 + r;
    const int rowB = rowA + 16;
    #pragma unroll
    for (int ni = 0; ni < 4; ni++) {
      ATT[(size_t)rowA * 512 + h * 64 + ni * 16 + l16] = f2bf(OfA[ni][r] * invA);
      ATT[(size_t)rowB * 512 + h * 64 + ni * 16 + l16] = f2bf(OfB[ni][r] * invB);
    }
  }
}

// ============================================================
// Kernel 3 v4: OUT = ATT(bf16) @ Wout^T + bias + ft(f32) -> f32
// 512 threads / 8 waves, 128x128 tile, wave-tile 32x64.
// Depth-2 counted-vmcnt pipeline (unchanged from round 12).
// ============================================================
__global__ __launch_bounds__(512) void out_proj(
    const u16* __restrict__ A, const u16* __restrict__ Wt,
    const float* __restrict__ Bias, const float* __restrict__ FT,
    float* __restrict__ OUT) {
  __shared__ u16 As[3][128][32];  // 8 KB/buf
  __shared__ u16 Ws[3][128][32];  // 8 KB/buf -> 48 KB total
  const int t = threadIdx.x;
  const int lid = blockIdx.y * 4 + blockIdx.x;        // 0..511
  const int sid = (lid & 7) * 64 + (lid >> 3);        // bijective
  const int bm = (sid / 4) * 128, bn = (sid % 4) * 128;
  const int w = t >> 6, lane = t & 63, quad = lane >> 4, l16 = lane & 15;
  const int mtb = (w >> 1) * 32, ntb = (w & 1) * 64;  // wave tile 32x64
  const int rr = lane >> 2;
  const int gch = ((lane & 3) ^ ((lane >> 3) & 3)) * 8;
  const int sw = (quad ^ ((l16 >> 1) & 3)) * 8;

  const u16* ag = A + (size_t)(bm + w * 16 + rr) * 512 + gch;
  const u16* wg = Wt + (size_t)(bn + w * 16 + rr) * 512 + gch;

  f32x4 acc[2][4];
  const f32x4 z4 = {0.f, 0.f, 0.f, 0.f};
  #pragma unroll
  for (int mi = 0; mi < 2; mi++)
    #pragma unroll
    for (int ni = 0; ni < 4; ni++) acc[mi][ni] = z4;

  // ---- prologue: issue steps 0 and 1; wait only for step 0 ----
  gl16(ag, &As[0][w * 16][0]);      gl16(wg, &Ws[0][w * 16][0]);
  gl16(ag + 32, &As[1][w * 16][0]); gl16(wg + 32, &Ws[1][w * 16][0]);
  asm volatile("s_waitcnt vmcnt(2)" ::: "memory");
  __builtin_amdgcn_s_barrier();

  for (int k = 0; k < 16; ++k) {
    const int cur = k % 3;
    if (k < 14) {                  // issue step k+2 (stays in flight)
      const int nx2 = (k + 2) % 3;
      const int kn = (k + 2) * 32;
      gl16(ag + kn, &As[nx2][w * 16][0]);
      gl16(wg + kn, &Ws[nx2][w * 16][0]);
    }
    short8 af[2], bf4[4];
    #pragma unroll
    for (int mi = 0; mi < 2; mi++)
      af[mi] = *(const short8*)&As[cur][mtb + mi * 16 + l16][sw];
    #pragma unroll
    for (int ni = 0; ni < 4; ni++)
      bf4[ni] = *(const short8*)&Ws[cur][ntb + ni * 16 + l16][sw];
    #pragma unroll
    for (int mi = 0; mi < 2; mi++)
      #pragma unroll
      for (int ni = 0; ni < 4; ni++)
        acc[mi][ni] = MFMA16(af[mi], bf4[ni], acc[mi][ni]);
    if (k < 15) {
      if (k < 14) asm volatile("s_waitcnt vmcnt(2) lgkmcnt(0)" ::: "memory");
      else        asm volatile("s_waitcnt vmcnt(0) lgkmcnt(0)" ::: "memory");
      __builtin_amdgcn_s_barrier();
    }
  }

  #pragma unroll
  for (int ni = 0; ni < 4; ni++) {
    const int g = bn + ntb + ni * 16;
    const float bias = Bias[g + l16];
    #pragma unroll
    for (int mi = 0; mi < 2; mi++) {
      const int row0 = bm + mtb + mi * 16 + quad * 4;
      #pragma unroll
      for (int r = 0; r < 4; r++) {
        const size_t idx = (size_t)(row0 + r) * 512 + g + l16;
        OUT[idx] = acc[mi][ni][r] + bias + FT[idx];
      }
    }
  }
}

// ============================================================
extern "C" void kernel_launch(void* const* d_in, const int* in_sizes, int n_in,
                              void* d_out, int out_size, void* d_ws, size_t ws_size,
                              hipStream_t stream) {
  const float* ft    = (const float*)d_in[0];  // [16][1024][512] f32
  const float* w_qkv = (const float*)d_in[1];  // [512][1536]   f32
  const float* b_qkv = (const float*)d_in[2];  // [1536]        f32
  const float* w_out = (const float*)d_in[3];  // [512][512]    f32
  const float* b_out = (const float*)d_in[4];  // [512]         f32
  float* out = (float*)d_out;                  // [16][1024][512] f32

  char* p = (char*)d_ws;
  u16* Xbf    = (u16*)(p);                              // 16,777,216
  u16* ATT    = Xbf;                                    // alias (Xbf dead)
  u16* Wqkv_t = (u16*)(p + 16777216);                   //  1,572,864
  u16* Wout_t = (u16*)(p + 18350080);                   //    524,288
  u16* Qp     = (u16*)(p + 18874368);                   // 16,777,216 (pre-scaled)
  u16* Kp     = (u16*)(p + 35651584);                   // 16,777,216
  u16* Vt     = (u16*)(p + 52428800);                   // 16,777,216 -> 69.2 MB

  conv_x     <<<4096, 256, 0, stream>>>(ft, Xbf);
  transpose_w<<<dim3(48, 16, 2), 256, 0, stream>>>(w_qkv, w_out, Wqkv_t, Wout_t);
  qkv_gemm   <<<dim3(6, 128), 512, 0, stream>>>(Xbf, Wqkv_t, b_qkv, Qp, Kp, Vt);
  attn_mfma  <<<dim3(512), 512, 0, stream>>>(Qp, Kp, Vt, ATT);
  out_proj   <<<dim3(4, 128), 512, 0, stream>>>(ATT, Wout_t, b_out, ft, out);
}